// Round 2
// baseline (100.554 us; speedup 1.0000x reference)
//
#include <hip/hip_runtime.h>

#define TOKENS 16384
#define KDIM   2048
#define NEXP   64
#define TOPK   6
#define BM     128   // tokens per block
#define BKT    32    // k per tile (double-buffered)

// direct global->LDS DMA, 16B per lane, linear LDS dest (wave-uniform base + lane*16)
__device__ __forceinline__ void g2l16(const float* g, float* l) {
  __builtin_amdgcn_global_load_lds(
      (const __attribute__((address_space(1))) float*)g,
      (__attribute__((address_space(3))) float*)l, 16, 0, 0);
}

// ---- block-end reduction helpers (compile-time quarter index: no scratch) ----
template<int Q>
__device__ __forceinline__ void red_write(const float acc[16][8], float4* buf4, int lane) {
#pragma unroll
  for (int il = 0; il < 4; ++il) {
    buf4[Q*512 + (il*2+0)*64 + lane] =
        make_float4(acc[Q*4+il][0], acc[Q*4+il][1], acc[Q*4+il][2], acc[Q*4+il][3]);
    buf4[Q*512 + (il*2+1)*64 + lane] =
        make_float4(acc[Q*4+il][4], acc[Q*4+il][5], acc[Q*4+il][6], acc[Q*4+il][7]);
  }
}
template<int Q>
__device__ __forceinline__ void red_add(float acc[16][8], const float4* buf4, int lane) {
#pragma unroll
  for (int il = 0; il < 4; ++il) {
    float4 a = buf4[Q*512 + (il*2+0)*64 + lane];
    float4 b = buf4[Q*512 + (il*2+1)*64 + lane];
    acc[Q*4+il][0]+=a.x; acc[Q*4+il][1]+=a.y; acc[Q*4+il][2]+=a.z; acc[Q*4+il][3]+=a.w;
    acc[Q*4+il][4]+=b.x; acc[Q*4+il][5]+=b.y; acc[Q*4+il][6]+=b.z; acc[Q*4+il][7]+=b.w;
  }
}
template<int Q>
__device__ __forceinline__ void part_store(const float acc[16][8], float* pp) {
#pragma unroll
  for (int il = 0; il < 4; ++il) {
    float* p = pp + (size_t)(Q*4 + il) * NEXP;
    *(float4*)(p)     = make_float4(acc[Q*4+il][0], acc[Q*4+il][1], acc[Q*4+il][2], acc[Q*4+il][3]);
    *(float4*)(p + 4) = make_float4(acc[Q*4+il][4], acc[Q*4+il][5], acc[Q*4+il][6], acc[Q*4+il][7]);
  }
}

// Kernel 1: block = 128 tokens x 64 experts x Kc. 4 waves split K (8 k each per
// 32-k tile). Thread: 16 tok x 8 exp = 128 acc. x staged via global_load_lds
// with XOR-swizzled SOURCE (linear LDS dest), read b128-along-k conflict-free.
// Block-end: 3-round LDS tree reduction of the 4 wave-partials, then one store.
__global__ __launch_bounds__(256, 2)
void moe_gemm_ws(const float* __restrict__ x, const float* __restrict__ wg,
                 float* __restrict__ part, int Kc) {
  __shared__ float xs[2 * BM * BKT];    // [b][tok][8 slots x float4]  32 KB
  __shared__ float ws[2 * BKT * NEXP];  // [b][k][64]                  16 KB

  const int t    = threadIdx.x;
  const int lane = t & 63;
  const int wid  = t >> 6;
  const int le   = lane & 7;    // expert group: experts le*8..+7
  const int tg   = lane >> 3;   // token group: tokens tg*16..+15
  const int row0 = blockIdx.x * BM;
  const int k0   = blockIdx.y * Kc;

  const int srow = lane >> 3;   // x staging: token offset in 8-row group
  const int sg   = lane & 7;    // x staging: k-granule (16B)
  const int wrow = lane >> 4;   // w staging: k-row offset
  const int wgr  = lane & 15;   // w staging: granule

  float acc[16][8];
#pragma unroll
  for (int i = 0; i < 16; ++i)
#pragma unroll
    for (int j = 0; j < 8; ++j) acc[i][j] = 0.f;

  const int nt = Kc / BKT;

  auto stage = [&](int b, int kbase) {
#pragma unroll
    for (int j = 0; j < 4; ++j) {              // x: 8 tokens x 8 granules per instr
      const int tok0 = wid * 32 + j * 8;
      const int tgc  = (tok0 >> 4) & 7;        // tg of these tokens (uniform)
      g2l16(x + (size_t)(row0 + tok0 + srow) * KDIM + kbase + ((sg ^ tgc) << 2),
            xs + b * 4096 + tok0 * 32);
    }
#pragma unroll
    for (int j = 0; j < 2; ++j) {              // w: 4 k-rows x 16 granules per instr
      const int kr0 = wid * 8 + j * 4;
      g2l16(wg + (size_t)(kbase + kr0 + wrow) * NEXP + (wgr << 2),
            ws + b * 2048 + kr0 * 64);
    }
  };

  stage(0, k0);

  for (int tt = 0; tt < nt; ++tt) {
    asm volatile("s_waitcnt vmcnt(0)" ::: "memory");  // DMA for tile tt complete
    __syncthreads();                                  // + all reads of buf b^1 done
    if (tt + 1 < nt) stage((tt + 1) & 1, k0 + (tt + 1) * BKT);

    const int b = tt & 1;
    const float4* xb = (const float4*)xs + b * 1024 + tg * 16 * 8;
    const float4* wb = (const float4*)ws + b * 512 + le * 2;

    __builtin_amdgcn_s_setprio(1);
#pragma unroll
    for (int kq = 0; kq < 2; ++kq) {
      const int kb = wid * 2 + kq;          // this wave's k-block (4 k)
      float4 wv[4][2];
#pragma unroll
      for (int kk = 0; kk < 4; ++kk) {
        wv[kk][0] = wb[(kb * 4 + kk) * 16];
        wv[kk][1] = wb[(kb * 4 + kk) * 16 + 1];
      }
      const float4* xp = xb + (kb ^ tg);    // swizzled slot -> holds k-block kb
#pragma unroll
      for (int i = 0; i < 16; ++i) {
        const float4 xv = xp[i * 8];
#pragma unroll
        for (int kk = 0; kk < 4; ++kk) {
          const float xk = ((const float*)&xv)[kk];
#pragma unroll
          for (int j = 0; j < 4; ++j) {
            acc[i][j]     += xk * ((const float*)&wv[kk][0])[j];
            acc[i][j + 4] += xk * ((const float*)&wv[kk][1])[j];
          }
        }
      }
    }
    __builtin_amdgcn_s_setprio(0);
  }

  // ---- reduce the 4 wave-partials (each wave ends owning token-quarter wid) ----
  __syncthreads();                  // all compute reads done; xs reusable (32 KB)
  float4* buf4 = (float4*)xs;
#pragma unroll
  for (int jr = 1; jr < 4; ++jr) {
    const int qw = (wid + jr) & 3;  // quarter this wave contributes this round
    switch (qw) {
      case 0: red_write<0>(acc, buf4, lane); break;
      case 1: red_write<1>(acc, buf4, lane); break;
      case 2: red_write<2>(acc, buf4, lane); break;
      case 3: red_write<3>(acc, buf4, lane); break;
    }
    __syncthreads();
    switch (wid) {
      case 0: red_add<0>(acc, buf4, lane); break;
      case 1: red_add<1>(acc, buf4, lane); break;
      case 2: red_add<2>(acc, buf4, lane); break;
      case 3: red_add<3>(acc, buf4, lane); break;
    }
    if (jr < 3) __syncthreads();
  }

  float* pp = part + ((size_t)blockIdx.y * TOKENS + row0 + tg * 16) * NEXP + le * 8;
  switch (wid) {
    case 0: part_store<0>(acc, pp); break;
    case 1: part_store<1>(acc, pp); break;
    case 2: part_store<2>(acc, pp); break;
    case 3: part_store<3>(acc, pp); break;
  }
}

// Kernel 2: 16 lanes per token, 4 experts/lane (float4 loads).
// Butterfly reductions within 16-lane groups; 6 argmax rounds with jax
// tie-break (equal score -> lower index). out: indices then scores.
__global__ __launch_bounds__(256)
void moe_softmax_topk(const float* __restrict__ part, float* __restrict__ out, int ns) {
  const int lane = threadIdx.x & 63;
  const int wid  = threadIdx.x >> 6;
  const int sub  = lane & 15;
  const int tok  = blockIdx.x * 16 + wid * 4 + (lane >> 4);

  float v[4] = {0.f, 0.f, 0.f, 0.f};
  for (int ks = 0; ks < ns; ++ks) {
    const float4 p = *(const float4*)(part + ((size_t)ks * TOKENS + tok) * NEXP + sub * 4);
    v[0] += p.x; v[1] += p.y; v[2] += p.z; v[3] += p.w;
  }

  float m = fmaxf(fmaxf(v[0], v[1]), fmaxf(v[2], v[3]));
#pragma unroll
  for (int off = 1; off < 16; off <<= 1) m = fmaxf(m, __shfl_xor(m, off));
  float p0 = expf(v[0] - m), p1 = expf(v[1] - m), p2 = expf(v[2] - m), p3 = expf(v[3] - m);
  float s = p0 + p1 + p2 + p3;
#pragma unroll
  for (int off = 1; off < 16; off <<= 1) s += __shfl_xor(s, off);
  v[0] = p0 / s; v[1] = p1 / s; v[2] = p2 / s; v[3] = p3 / s;

  float resv = 0.f; int resi = 0;
#pragma unroll
  for (int rr = 0; rr < TOPK; ++rr) {
    float bv = v[0]; int bi = sub * 4;
#pragma unroll
    for (int j = 1; j < 4; ++j)
      if (v[j] > bv) { bv = v[j]; bi = sub * 4 + j; }
#pragma unroll
    for (int off = 1; off < 16; off <<= 1) {
      const float ov = __shfl_xor(bv, off);
      const int   oi = __shfl_xor(bi, off);
      if (ov > bv || (ov == bv && oi < bi)) { bv = ov; bi = oi; }
    }
    if (sub == rr) { resv = bv; resi = bi; }
    if ((bi >> 2) == sub) v[bi & 3] = -1.f;
  }

  if (sub < TOPK) {
    out[(size_t)tok * TOPK + sub] = (float)resi;
    out[(size_t)TOKENS * TOPK + (size_t)tok * TOPK + sub] = resv;
  }
}

extern "C" void kernel_launch(void* const* d_in, const int* in_sizes, int n_in,
                              void* d_out, int out_size, void* d_ws, size_t ws_size,
                              hipStream_t stream) {
  const float* x  = (const float*)d_in[0];
  const float* wg = (const float*)d_in[1];
  float* out  = (float*)d_out;
  float* part = (float*)d_ws;

  int ns = 4;
  while (ns > 1 && (size_t)ns * TOKENS * NEXP * sizeof(float) > ws_size) ns >>= 1;
  const int Kc = KDIM / ns;

  dim3 g1(TOKENS / BM, ns);
  moe_gemm_ws<<<g1, dim3(256), 0, stream>>>(x, wg, part, Kc);
  moe_softmax_topk<<<dim3(TOKENS / 16), dim3(256), 0, stream>>>(part, out, ns);
}

// Round 4
// 77.735 us; speedup vs baseline: 1.2936x; 1.2936x over previous
//
#include <hip/hip_runtime.h>

#define TOKENS 16384
#define KDIM   2048
#define NEXP   64
#define TOPK   6
#define KSTEP  32                 // k per MFMA step
#define NSTEPS (KDIM / KSTEP)     // 64
#define CHUNK  4                  // K-steps per staged chunk
#define NCH    (NSTEPS / CHUNK)   // 16
#define BM     64                 // tokens per block

typedef short short8 __attribute__((ext_vector_type(8)));   // 8 bf16 = 4 VGPR
typedef float f32x4  __attribute__((ext_vector_type(4)));

// Exact 3-way truncation split: f == bf(h) + bf(l) + bf(l2) + eps, |eps| <= 2^-24 |f|.
// Truncation (bit slice) keeps r1, r2 exactly representable -> no rne needed.
__device__ __forceinline__ void split3(float f, short& h, short& l, short& l2) {
  const unsigned u = __builtin_bit_cast(unsigned, f);
  h = (short)(u >> 16);
  const float r1 = f - __builtin_bit_cast(float, u & 0xffff0000u);
  const unsigned u1 = __builtin_bit_cast(unsigned, r1);
  l = (short)(u1 >> 16);
  const float r2 = r1 - __builtin_bit_cast(float, u1 & 0xffff0000u);
  l2 = (short)(__builtin_bit_cast(unsigned, r2) >> 16);
}

__device__ __forceinline__ void g2l16(const void* g, void* l) {
  __builtin_amdgcn_global_load_lds(
      (const __attribute__((address_space(1))) unsigned*)g,
      (__attribute__((address_space(3))) unsigned*)l, 16, 0, 0);
}

// Kernel 0: pack W into MFMA-B-fragment order, 3-term bf16 split.
// w*[s][nt][lane][j] = term of W[s*32 + (lane>>4)*8 + j][nt*16 + (lane&15)]
__global__ __launch_bounds__(256)
void moe_wpack(const float* __restrict__ wg, short* __restrict__ wh,
               short* __restrict__ wl, short* __restrict__ wl2) {
  const int tid = blockIdx.x * 256 + threadIdx.x;  // 0..16383 = (s, nt, lane)
  const int l  = tid & 63;
  const int nt = (tid >> 6) & 3;
  const int s  = tid >> 8;
  short8 a, b, c;
#pragma unroll
  for (int j = 0; j < 8; ++j) {
    const int k = s * 32 + (l >> 4) * 8 + j;
    const int n = nt * 16 + (l & 15);
    short x, y, z;
    split3(wg[(size_t)k * NEXP + n], x, y, z);
    a[j] = x; b[j] = y; c[j] = z;
  }
  *(short8*)(wh  + (size_t)tid * 8) = a;
  *(short8*)(wl  + (size_t)tid * 8) = b;
  *(short8*)(wl2 + (size_t)tid * 8) = c;
}

// Kernel 1: fused MFMA GEMM (6-term bf16 split, 2 accumulators) + softmax + top-k.
// Block = 64 tokens x 64 experts x K=2048; wave w owns tokens w*16..+15.
// x: HBM -> LDS via global_load_lds, XOR-pre-swizzled source; w: fragment-ordered
// bf16 terms loaded global->VGPR (L2/L1-hot, identical stream for all waves).
__global__ __launch_bounds__(256)
void moe_mfma(const float* __restrict__ x, const short* __restrict__ wh,
              const short* __restrict__ wl, const short* __restrict__ wl2,
              float* __restrict__ out) {
  __shared__ float xs[2 * CHUNK * BM * KSTEP];   // 64 KB, double-buffered

  const int t    = threadIdx.x;
  const int lane = t & 63;
  const int wid  = t >> 6;
  const int row0 = blockIdx.x * BM;

  auto stage = [&](int buf, int c) {
    // 2048 granules (16B): G = (stp, tok, slot); src granule = slot ^ (tok&7)
#pragma unroll
    for (int j = 0; j < 8; ++j) {
      const int G = j * 256 + t;
      const int stp = G >> 9, rem = G & 511;
      const int tok = rem >> 3, slot = rem & 7;
      const int g = slot ^ (tok & 7);
      g2l16(x + (size_t)(row0 + tok) * KDIM + c * (CHUNK * KSTEP) + stp * KSTEP + g * 4,
            xs + (size_t)buf * (CHUNK * BM * KSTEP) + (size_t)G * 4);
    }
  };

  f32x4 accB[4] = {};   // hh term (magnitude ~1)
  f32x4 accS[4] = {};   // correction terms (magnitude ~2^-8)
  const int trow = wid * 16 + (lane & 15);   // my A-row (local token)
  const int kb   = lane >> 4;                // my k-group of 8
  const int sw   = trow & 7;

  const short8* whv  = (const short8*)wh;
  const short8* wlv  = (const short8*)wl;
  const short8* wl2v = (const short8*)wl2;

  stage(0, 0);

  for (int c = 0; c < NCH; ++c) {
    asm volatile("s_waitcnt vmcnt(0)" ::: "memory");   // chunk c DMA complete
    __syncthreads();                                   // + all reads of other buf done
    if (c + 1 < NCH) stage((c + 1) & 1, c + 1);
    const int buf = c & 1;

#pragma unroll
    for (int stp = 0; stp < CHUNK; ++stp) {
      const int s = c * CHUNK + stp;
      // w fragments: 12 coalesced b128 loads (L2/L1-hot after first block pass)
      short8 bh[4], bl[4], bl2[4];
#pragma unroll
      for (int nt = 0; nt < 4; ++nt) {
        const size_t fi = (size_t)(s * 4 + nt) * 64 + lane;
        bh[nt]  = whv[fi];
        bl[nt]  = wlv[fi];
        bl2[nt] = wl2v[fi];
      }
      // x: 8 k-values, split 3-way
      const float* xrow = xs + (size_t)(buf * CHUNK + stp) * (BM * KSTEP) + trow * KSTEP;
      const float4 xa = *(const float4*)(xrow + (((kb * 2)     ^ sw) << 2));
      const float4 xb = *(const float4*)(xrow + (((kb * 2 + 1) ^ sw) << 2));
      short8 ah, al, al2;
#pragma unroll
      for (int e = 0; e < 4; ++e) {
        short h0, l0, m0, h1, l1, m1;
        split3(((const float*)&xa)[e], h0, l0, m0);
        split3(((const float*)&xb)[e], h1, l1, m1);
        ah[e] = h0; al[e] = l0; al2[e] = m0;
        ah[e + 4] = h1; al[e + 4] = l1; al2[e + 4] = m1;
      }
#pragma unroll
      for (int nt = 0; nt < 4; ++nt) {
        accB[nt] = __builtin_amdgcn_mfma_f32_16x16x32_bf16(ah,  bh[nt],  accB[nt], 0, 0, 0);
        accS[nt] = __builtin_amdgcn_mfma_f32_16x16x32_bf16(al,  bh[nt],  accS[nt], 0, 0, 0);
        accS[nt] = __builtin_amdgcn_mfma_f32_16x16x32_bf16(ah,  bl[nt],  accS[nt], 0, 0, 0);
        accS[nt] = __builtin_amdgcn_mfma_f32_16x16x32_bf16(al,  bl[nt],  accS[nt], 0, 0, 0);
        accS[nt] = __builtin_amdgcn_mfma_f32_16x16x32_bf16(ah,  bl2[nt], accS[nt], 0, 0, 0);
        accS[nt] = __builtin_amdgcn_mfma_f32_16x16x32_bf16(al2, bh[nt],  accS[nt], 0, 0, 0);
      }
    }
  }

  // ---- fused softmax + top-k. D: col=lane&15 (expert within nt),
  // row=(lane>>4)*4+reg (token). Each 16-lane group handles 4 tokens.
  const int sub = lane & 15;
  const int grp = lane >> 4;
#pragma unroll
  for (int r = 0; r < 4; ++r) {
    const int tok = row0 + wid * 16 + grp * 4 + r;
    float v[4];
#pragma unroll
    for (int nt = 0; nt < 4; ++nt) v[nt] = accB[nt][r] + accS[nt][r];

    float m = fmaxf(fmaxf(v[0], v[1]), fmaxf(v[2], v[3]));
#pragma unroll
    for (int off = 1; off < 16; off <<= 1) m = fmaxf(m, __shfl_xor(m, off));
    const float p0 = expf(v[0] - m), p1 = expf(v[1] - m);
    const float p2 = expf(v[2] - m), p3 = expf(v[3] - m);
    float s = p0 + p1 + p2 + p3;
#pragma unroll
    for (int off = 1; off < 16; off <<= 1) s += __shfl_xor(s, off);
    v[0] = p0 / s; v[1] = p1 / s; v[2] = p2 / s; v[3] = p3 / s;

    float resv = 0.f; int resi = 0;
#pragma unroll
    for (int rr = 0; rr < TOPK; ++rr) {
      float bv = v[0]; int bi = sub;              // expert = nt*16 + sub
#pragma unroll
      for (int nt = 1; nt < 4; ++nt)
        if (v[nt] > bv) { bv = v[nt]; bi = nt * 16 + sub; }  // strict >: low idx on tie
#pragma unroll
      for (int off = 1; off < 16; off <<= 1) {
        const float ov = __shfl_xor(bv, off);
        const int   oi = __shfl_xor(bi, off);
        if (ov > bv || (ov == bv && oi < bi)) { bv = ov; bi = oi; }
      }
      if (sub == rr) { resv = bv; resi = bi; }
      if ((bi & 15) == sub) v[bi >> 4] = -1.f;    // scores > 0, sentinel safe
    }
    if (sub < TOPK) {
      out[(size_t)tok * TOPK + sub] = (float)resi;
      out[(size_t)TOKENS * TOPK + (size_t)tok * TOPK + sub] = resv;
    }
  }
}

extern "C" void kernel_launch(void* const* d_in, const int* in_sizes, int n_in,
                              void* d_out, int out_size, void* d_ws, size_t ws_size,
                              hipStream_t stream) {
  const float* x  = (const float*)d_in[0];
  const float* wg = (const float*)d_in[1];
  float* out = (float*)d_out;
  short* wh  = (short*)d_ws;                        // 3 x 131072 shorts = 768 KB
  short* wl  = wh + (size_t)NSTEPS * 4 * 64 * 8;
  short* wl2 = wl + (size_t)NSTEPS * 4 * 64 * 8;

  moe_wpack<<<dim3(64), dim3(256), 0, stream>>>(wg, wh, wl, wl2);
  moe_mfma<<<dim3(TOKENS / BM), dim3(256), 0, stream>>>(x, wh, wl, wl2, out);
}

// Round 5
// 76.190 us; speedup vs baseline: 1.3198x; 1.0203x over previous
//
#include <hip/hip_runtime.h>

#define TOKENS 16384
#define KDIM   2048
#define NEXP   64
#define TOPK   6
#define KSTEP  32                 // k per MFMA step
#define NSTEPS (KDIM / KSTEP)     // 64
#define CHUNK  2                  // K-steps per staged chunk
#define NCH    (NSTEPS / CHUNK)   // 32
#define BM     64                 // tokens per block
#define XSB    (CHUNK * BM * KSTEP)   // floats per x buffer (4096)

typedef short short8 __attribute__((ext_vector_type(8)));   // 8 bf16 = 4 VGPR
typedef float f32x4  __attribute__((ext_vector_type(4)));

// Exact 3-way truncation split: f == bf(h) + bf(l) + bf(l2) + eps, |eps| <= 2^-24 |f|.
__device__ __forceinline__ void split3(float f, short& h, short& l, short& l2) {
  const unsigned u = __builtin_bit_cast(unsigned, f);
  h = (short)(u >> 16);
  const float r1 = f - __builtin_bit_cast(float, u & 0xffff0000u);
  const unsigned u1 = __builtin_bit_cast(unsigned, r1);
  l = (short)(u1 >> 16);
  const float r2 = r1 - __builtin_bit_cast(float, u1 & 0xffff0000u);
  l2 = (short)(__builtin_bit_cast(unsigned, r2) >> 16);
}

__device__ __forceinline__ void g2l16(const void* g, void* l) {
  __builtin_amdgcn_global_load_lds(
      (const __attribute__((address_space(1))) unsigned*)g,
      (__attribute__((address_space(3))) unsigned*)l, 16, 0, 0);
}

// Kernel 0: pack W into MFMA-B-fragment order, 3-term bf16 split.
// w*[s][nt][lane][j] = term of W[s*32 + (lane>>4)*8 + j][nt*16 + (lane&15)]
__global__ __launch_bounds__(256)
void moe_wpack(const float* __restrict__ wg, short* __restrict__ wh,
               short* __restrict__ wl, short* __restrict__ wl2) {
  const int tid = blockIdx.x * 256 + threadIdx.x;  // 0..16383 = (s, nt, lane)
  const int l  = tid & 63;
  const int nt = (tid >> 6) & 3;
  const int s  = tid >> 8;
  short8 a, b, c;
#pragma unroll
  for (int j = 0; j < 8; ++j) {
    const int k = s * 32 + (l >> 4) * 8 + j;
    const int n = nt * 16 + (l & 15);
    short x, y, z;
    split3(wg[(size_t)k * NEXP + n], x, y, z);
    a[j] = x; b[j] = y; c[j] = z;
  }
  *(short8*)(wh  + (size_t)tid * 8) = a;
  *(short8*)(wl  + (size_t)tid * 8) = b;
  *(short8*)(wl2 + (size_t)tid * 8) = c;
}

// Kernel 1: fused MFMA GEMM (6-term bf16 split) + softmax + top-k.
// Per iteration (64 k): [24 w-frag loads] -> [stage x chunk c+1 via DMA] ->
// vmcnt(28) (retires ONLY the 4 oldest = DMA(c), in-order queue) -> barrier ->
// compute. w-uses wait at most vmcnt(4): the in-flight stage never drains.
// Triple-buffered xs so stage(c+1) issues before the DMA(c) wait.
__global__ __launch_bounds__(256, 1)
void moe_mfma(const float* __restrict__ x, const short* __restrict__ wh,
              const short* __restrict__ wl, const short* __restrict__ wl2,
              float* __restrict__ out) {
  __shared__ float xs[3 * XSB];   // 48 KB, triple-buffered

  const int t    = threadIdx.x;
  const int lane = t & 63;
  const int wid  = t >> 6;
  const int row0 = blockIdx.x * BM;

  auto stage = [&](int b, int c) {
    // 1024 granules (16B): G = (stp, tok, slot); src granule = slot ^ (tok&7)
#pragma unroll
    for (int j = 0; j < 4; ++j) {
      const int G = j * 256 + t;
      const int stp = G >> 9, rem = G & 511;
      const int tok = rem >> 3, slot = rem & 7;
      const int g = slot ^ (tok & 7);
      g2l16(x + (size_t)(row0 + tok) * KDIM + c * (CHUNK * KSTEP) + stp * KSTEP + g * 4,
            xs + (size_t)b * XSB + (size_t)G * 4);
    }
  };

  f32x4 accB[4] = {};   // hh term (magnitude ~1)
  f32x4 accS[4] = {};   // correction terms (magnitude ~2^-8)
  const int trow = wid * 16 + (lane & 15);   // my A-row (local token)
  const int kb   = lane >> 4;                // my k-group of 8
  const int sw   = trow & 7;

  const short8* __restrict__ whv  = (const short8*)wh;
  const short8* __restrict__ wlv  = (const short8*)wl;
  const short8* __restrict__ wl2v = (const short8*)wl2;

  stage(0, 0);

  int bc = 0;                                // buffer holding chunk c
  for (int c = 0; c < NCH; ++c) {
    // 1) w fragments for chunk c (both steps) — issued BEFORE the next stage
    short8 bh[2][4], bl[2][4], bl2[2][4];
#pragma unroll
    for (int stp = 0; stp < CHUNK; ++stp)
#pragma unroll
      for (int nt = 0; nt < 4; ++nt) {
        const int fi = c * 512 + stp * 256 + nt * 64 + lane;
        bh[stp][nt]  = whv[fi];
        bl[stp][nt]  = wlv[fi];
        bl2[stp][nt] = wl2v[fi];
      }
    __builtin_amdgcn_sched_barrier(0);

    // 2) stage chunk c+1, then retire only DMA(c) (oldest 4 in the queue)
    const int bn = (bc == 2) ? 0 : bc + 1;
    if (c + 1 < NCH) {
      stage(bn, c + 1);
      __builtin_amdgcn_sched_barrier(0);
      asm volatile("s_waitcnt vmcnt(28)" ::: "memory");  // 24 w + 4 new DMA remain
    } else {
      asm volatile("s_waitcnt vmcnt(24)" ::: "memory");  // 24 w remain
    }
    __syncthreads();   // buf bc fully written (every wave waited its own DMA)

    // 3) compute chunk c from buf bc
#pragma unroll
    for (int stp = 0; stp < CHUNK; ++stp) {
      const float* xrow = xs + (size_t)bc * XSB + stp * (BM * KSTEP) + trow * KSTEP;
      const float4 xa = *(const float4*)(xrow + (((kb * 2)     ^ sw) << 2));
      const float4 xb = *(const float4*)(xrow + (((kb * 2 + 1) ^ sw) << 2));
      short8 ah, al, al2;
#pragma unroll
      for (int e = 0; e < 4; ++e) {
        short h0, l0, m0, h1, l1, m1;
        split3(((const float*)&xa)[e], h0, l0, m0);
        split3(((const float*)&xb)[e], h1, l1, m1);
        ah[e] = h0; al[e] = l0; al2[e] = m0;
        ah[e + 4] = h1; al[e + 4] = l1; al2[e + 4] = m1;
      }
#pragma unroll
      for (int nt = 0; nt < 4; ++nt) {
        accB[nt] = __builtin_amdgcn_mfma_f32_16x16x32_bf16(ah,  bh[stp][nt],  accB[nt], 0, 0, 0);
        accS[nt] = __builtin_amdgcn_mfma_f32_16x16x32_bf16(al,  bh[stp][nt],  accS[nt], 0, 0, 0);
        accS[nt] = __builtin_amdgcn_mfma_f32_16x16x32_bf16(ah,  bl[stp][nt],  accS[nt], 0, 0, 0);
        accS[nt] = __builtin_amdgcn_mfma_f32_16x16x32_bf16(al,  bl[stp][nt],  accS[nt], 0, 0, 0);
        accS[nt] = __builtin_amdgcn_mfma_f32_16x16x32_bf16(ah,  bl2[stp][nt], accS[nt], 0, 0, 0);
        accS[nt] = __builtin_amdgcn_mfma_f32_16x16x32_bf16(al2, bh[stp][nt],  accS[nt], 0, 0, 0);
      }
    }
    bc = bn;
  }

  // ---- fused softmax + top-k. D: col=lane&15 (expert within nt),
  // row=(lane>>4)*4+reg (token). Each 16-lane group handles 4 tokens.
  const int sub = lane & 15;
  const int grp = lane >> 4;
#pragma unroll
  for (int r = 0; r < 4; ++r) {
    const int tok = row0 + wid * 16 + grp * 4 + r;
    float v[4];
#pragma unroll
    for (int nt = 0; nt < 4; ++nt) v[nt] = accB[nt][r] + accS[nt][r];

    float m = fmaxf(fmaxf(v[0], v[1]), fmaxf(v[2], v[3]));
#pragma unroll
    for (int off = 1; off < 16; off <<= 1) m = fmaxf(m, __shfl_xor(m, off));
    const float p0 = expf(v[0] - m), p1 = expf(v[1] - m);
    const float p2 = expf(v[2] - m), p3 = expf(v[3] - m);
    float s = p0 + p1 + p2 + p3;
#pragma unroll
    for (int off = 1; off < 16; off <<= 1) s += __shfl_xor(s, off);
    v[0] = p0 / s; v[1] = p1 / s; v[2] = p2 / s; v[3] = p3 / s;

    float resv = 0.f; int resi = 0;
#pragma unroll
    for (int rr = 0; rr < TOPK; ++rr) {
      float bv = v[0]; int bi = sub;              // expert = nt*16 + sub
#pragma unroll
      for (int nt = 1; nt < 4; ++nt)
        if (v[nt] > bv) { bv = v[nt]; bi = nt * 16 + sub; }  // strict >: low idx on tie
#pragma unroll
      for (int off = 1; off < 16; off <<= 1) {
        const float ov = __shfl_xor(bv, off);
        const int   oi = __shfl_xor(bi, off);
        if (ov > bv || (ov == bv && oi < bi)) { bv = ov; bi = oi; }
      }
      if (sub == rr) { resv = bv; resi = bi; }
      if ((bi & 15) == sub) v[bi >> 4] = -1.f;    // scores > 0, sentinel safe
    }
    if (sub < TOPK) {
      out[(size_t)tok * TOPK + sub] = (float)resi;
      out[(size_t)TOKENS * TOPK + (size_t)tok * TOPK + sub] = resv;
    }
  }
}

extern "C" void kernel_launch(void* const* d_in, const int* in_sizes, int n_in,
                              void* d_out, int out_size, void* d_ws, size_t ws_size,
                              hipStream_t stream) {
  const float* x  = (const float*)d_in[0];
  const float* wg = (const float*)d_in[1];
  float* out = (float*)d_out;
  short* wh  = (short*)d_ws;                        // 3 x 131072 shorts = 768 KB
  short* wl  = wh + (size_t)NSTEPS * 4 * 64 * 8;
  short* wl2 = wl + (size_t)NSTEPS * 4 * 64 * 8;

  moe_wpack<<<dim3(64), dim3(256), 0, stream>>>(wg, wh, wl, wl2);
  moe_mfma<<<dim3(TOKENS / BM), dim3(256), 0, stream>>>(x, wh, wl, wl2, out);
}

// Round 6
// 71.343 us; speedup vs baseline: 1.4094x; 1.0679x over previous
//
#include <hip/hip_runtime.h>

#define TOKENS 16384
#define KDIM   2048
#define NEXP   64
#define TOPK   6
#define KSTEP  32                 // k per MFMA step
#define NSTEPS (KDIM / KSTEP)     // 64
#define CHUNK  2                  // K-steps per staged chunk
#define NCH    (NSTEPS / CHUNK)   // 32
#define BM     64                 // tokens per block
#define XSB    (CHUNK * BM * KSTEP)   // floats per x buffer (4096)

typedef short short8 __attribute__((ext_vector_type(8)));   // 8 bf16 = 4 VGPR
typedef float f32x4  __attribute__((ext_vector_type(4)));

// Exact 3-way truncation split: f == bf(h) + bf(l) + bf(l2) + eps, |eps| <= 2^-24 |f|.
__device__ __forceinline__ void split3(float f, short& h, short& l, short& l2) {
  const unsigned u = __builtin_bit_cast(unsigned, f);
  h = (short)(u >> 16);
  const float r1 = f - __builtin_bit_cast(float, u & 0xffff0000u);
  const unsigned u1 = __builtin_bit_cast(unsigned, r1);
  l = (short)(u1 >> 16);
  const float r2 = r1 - __builtin_bit_cast(float, u1 & 0xffff0000u);
  l2 = (short)(__builtin_bit_cast(unsigned, r2) >> 16);
}

__device__ __forceinline__ void g2l16(const void* g, void* l) {
  __builtin_amdgcn_global_load_lds(
      (const __attribute__((address_space(1))) unsigned*)g,
      (__attribute__((address_space(3))) unsigned*)l, 16, 0, 0);
}

// Kernel 0: pack W into MFMA-B-fragment order, 3-term bf16 split.
// w*[s][nt][lane][j] = term of W[s*32 + (lane>>4)*8 + j][nt*16 + (lane&15)]
__global__ __launch_bounds__(256)
void moe_wpack(const float* __restrict__ wg, short* __restrict__ wh,
               short* __restrict__ wl, short* __restrict__ wl2) {
  const int tid = blockIdx.x * 256 + threadIdx.x;  // 0..16383 = (s, nt, lane)
  const int l  = tid & 63;
  const int nt = (tid >> 6) & 3;
  const int s  = tid >> 8;
  short8 a, b, c;
#pragma unroll
  for (int j = 0; j < 8; ++j) {
    const int k = s * 32 + (l >> 4) * 8 + j;
    const int n = nt * 16 + (l & 15);
    short x, y, z;
    split3(wg[(size_t)k * NEXP + n], x, y, z);
    a[j] = x; b[j] = y; c[j] = z;
  }
  *(short8*)(wh  + (size_t)tid * 8) = a;
  *(short8*)(wl  + (size_t)tid * 8) = b;
  *(short8*)(wl2 + (size_t)tid * 8) = c;
}

// Kernel 1: fused MFMA GEMM (6-term bf16 split) + softmax + top-k.
// Per iteration: [24 w-frag loads] -> [stage x chunk c+1 via DMA] ->
// s_waitcnt vmcnt(28) (in-order queue: retires ONLY the 4 oldest = DMA(c)) ->
// RAW s_barrier (no compiler vmcnt(0) drain!) -> compute. DMA(c+1) + w stay
// in flight across the barrier. Triple-buffered xs covers the lag window.
__global__ __launch_bounds__(256, 1)
void moe_mfma(const float* __restrict__ x, const short* __restrict__ wh,
              const short* __restrict__ wl, const short* __restrict__ wl2,
              float* __restrict__ out) {
  __shared__ float xs[3 * XSB];   // 48 KB, triple-buffered

  const int t    = threadIdx.x;
  const int lane = t & 63;
  const int wid  = t >> 6;
  const int row0 = blockIdx.x * BM;

  auto stage = [&](int b, int c) {
    // 1024 granules (16B): G = (stp, tok, slot); src granule = slot ^ (tok&7)
#pragma unroll
    for (int j = 0; j < 4; ++j) {
      const int G = j * 256 + t;
      const int stp = G >> 9, rem = G & 511;
      const int tok = rem >> 3, slot = rem & 7;
      const int g = slot ^ (tok & 7);
      g2l16(x + (size_t)(row0 + tok) * KDIM + c * (CHUNK * KSTEP) + stp * KSTEP + g * 4,
            xs + (size_t)b * XSB + (size_t)G * 4);
    }
  };

  f32x4 accB[4] = {};   // hh term (magnitude ~1)
  f32x4 accS[4] = {};   // correction terms (magnitude ~2^-8)
  const int trow = wid * 16 + (lane & 15);   // my A-row (local token)
  const int kb   = lane >> 4;                // my k-group of 8
  const int sw   = trow & 7;

  const short8* __restrict__ whv  = (const short8*)wh;
  const short8* __restrict__ wlv  = (const short8*)wl;
  const short8* __restrict__ wl2v = (const short8*)wl2;

  stage(0, 0);

  int bc = 0;                                // buffer holding chunk c
  for (int c = 0; c < NCH; ++c) {
    // 1) w fragments for chunk c (both steps) — issued BEFORE the next stage
    short8 bh[2][4], bl[2][4], bl2[2][4];
#pragma unroll
    for (int stp = 0; stp < CHUNK; ++stp)
#pragma unroll
      for (int nt = 0; nt < 4; ++nt) {
        const int fi = c * 512 + stp * 256 + nt * 64 + lane;
        bh[stp][nt]  = whv[fi];
        bl[stp][nt]  = wlv[fi];
        bl2[stp][nt] = wl2v[fi];
      }
    __builtin_amdgcn_sched_barrier(0);

    // 2) stage chunk c+1, then retire only DMA(c) (oldest 4 in the queue)
    const int bn = (bc == 2) ? 0 : bc + 1;
    if (c + 1 < NCH) {
      stage(bn, c + 1);
      __builtin_amdgcn_sched_barrier(0);
      asm volatile("s_waitcnt vmcnt(28)" ::: "memory");  // 24 w + 4 new DMA remain
    } else {
      asm volatile("s_waitcnt vmcnt(24)" ::: "memory");  // 24 w remain
    }
    __builtin_amdgcn_sched_barrier(0);
    __builtin_amdgcn_s_barrier();       // RAW barrier: no vmcnt(0) drain
    __builtin_amdgcn_sched_barrier(0);

    // 3) compute chunk c from buf bc
#pragma unroll
    for (int stp = 0; stp < CHUNK; ++stp) {
      const float* xrow = xs + (size_t)bc * XSB + stp * (BM * KSTEP) + trow * KSTEP;
      const float4 xa = *(const float4*)(xrow + (((kb * 2)     ^ sw) << 2));
      const float4 xb = *(const float4*)(xrow + (((kb * 2 + 1) ^ sw) << 2));
      short8 ah, al, al2;
#pragma unroll
      for (int e = 0; e < 4; ++e) {
        short h0, l0, m0, h1, l1, m1;
        split3(((const float*)&xa)[e], h0, l0, m0);
        split3(((const float*)&xb)[e], h1, l1, m1);
        ah[e] = h0; al[e] = l0; al2[e] = m0;
        ah[e + 4] = h1; al[e + 4] = l1; al2[e + 4] = m1;
      }
#pragma unroll
      for (int nt = 0; nt < 4; ++nt) {
        accB[nt] = __builtin_amdgcn_mfma_f32_16x16x32_bf16(ah,  bh[stp][nt],  accB[nt], 0, 0, 0);
        accS[nt] = __builtin_amdgcn_mfma_f32_16x16x32_bf16(al,  bh[stp][nt],  accS[nt], 0, 0, 0);
        accS[nt] = __builtin_amdgcn_mfma_f32_16x16x32_bf16(ah,  bl[stp][nt],  accS[nt], 0, 0, 0);
        accS[nt] = __builtin_amdgcn_mfma_f32_16x16x32_bf16(al,  bl[stp][nt],  accS[nt], 0, 0, 0);
        accS[nt] = __builtin_amdgcn_mfma_f32_16x16x32_bf16(ah,  bl2[stp][nt], accS[nt], 0, 0, 0);
        accS[nt] = __builtin_amdgcn_mfma_f32_16x16x32_bf16(al2, bh[stp][nt],  accS[nt], 0, 0, 0);
      }
    }
    bc = bn;
  }

  // ---- fused softmax + top-k. D: col=lane&15 (expert within nt),
  // row=(lane>>4)*4+reg (token). Each 16-lane group handles 4 tokens.
  const int sub = lane & 15;
  const int grp = lane >> 4;
#pragma unroll
  for (int r = 0; r < 4; ++r) {
    const int tok = row0 + wid * 16 + grp * 4 + r;
    float v[4];
#pragma unroll
    for (int nt = 0; nt < 4; ++nt) v[nt] = accB[nt][r] + accS[nt][r];

    float m = fmaxf(fmaxf(v[0], v[1]), fmaxf(v[2], v[3]));
#pragma unroll
    for (int off = 1; off < 16; off <<= 1) m = fmaxf(m, __shfl_xor(m, off));
    const float p0 = expf(v[0] - m), p1 = expf(v[1] - m);
    const float p2 = expf(v[2] - m), p3 = expf(v[3] - m);
    float s = p0 + p1 + p2 + p3;
#pragma unroll
    for (int off = 1; off < 16; off <<= 1) s += __shfl_xor(s, off);
    v[0] = p0 / s; v[1] = p1 / s; v[2] = p2 / s; v[3] = p3 / s;

    float resv = 0.f; int resi = 0;
#pragma unroll
    for (int rr = 0; rr < TOPK; ++rr) {
      float bv = v[0]; int bi = sub;              // expert = nt*16 + sub
#pragma unroll
      for (int nt = 1; nt < 4; ++nt)
        if (v[nt] > bv) { bv = v[nt]; bi = nt * 16 + sub; }  // strict >: low idx on tie
#pragma unroll
      for (int off = 1; off < 16; off <<= 1) {
        const float ov = __shfl_xor(bv, off);
        const int   oi = __shfl_xor(bi, off);
        if (ov > bv || (ov == bv && oi < bi)) { bv = ov; bi = oi; }
      }
      if (sub == rr) { resv = bv; resi = bi; }
      if ((bi & 15) == sub) v[bi >> 4] = -1.f;    // scores > 0, sentinel safe
    }
    if (sub < TOPK) {
      out[(size_t)tok * TOPK + sub] = (float)resi;
      out[(size_t)TOKENS * TOPK + (size_t)tok * TOPK + sub] = resv;
    }
  }
}

extern "C" void kernel_launch(void* const* d_in, const int* in_sizes, int n_in,
                              void* d_out, int out_size, void* d_ws, size_t ws_size,
                              hipStream_t stream) {
  const float* x  = (const float*)d_in[0];
  const float* wg = (const float*)d_in[1];
  float* out = (float*)d_out;
  short* wh  = (short*)d_ws;                        // 3 x 131072 shorts = 768 KB
  short* wl  = wh + (size_t)NSTEPS * 4 * 64 * 8;
  short* wl2 = wl + (size_t)NSTEPS * 4 * 64 * 8;

  moe_wpack<<<dim3(64), dim3(256), 0, stream>>>(wg, wh, wl, wl2);
  moe_mfma<<<dim3(TOKENS / BM), dim3(256), 0, stream>>>(x, wh, wl, wl2, out);
}

// Round 7
// 52.413 us; speedup vs baseline: 1.9185x; 1.3612x over previous
//
#include <hip/hip_runtime.h>

#define TOKENS 16384
#define KDIM   2048
#define NEXP   64
#define TOPK   6
#define NSTEPS (KDIM / 32)        // 64 global K-steps
#define BM     64                 // tokens per block
#define XSB    (BM * 32)          // floats per x buffer (2048 = 8 KB)

typedef short short8 __attribute__((ext_vector_type(8)));   // 8 bf16 = 4 VGPR
typedef float f32x4  __attribute__((ext_vector_type(4)));

// Exact 3-way truncation split: f == bf(h) + bf(l) + bf(l2) + eps, |eps| <= 2^-24 |f|.
__device__ __forceinline__ void split3(float f, short& h, short& l, short& l2) {
  const unsigned u = __builtin_bit_cast(unsigned, f);
  h = (short)(u >> 16);
  const float r1 = f - __builtin_bit_cast(float, u & 0xffff0000u);
  const unsigned u1 = __builtin_bit_cast(unsigned, r1);
  l = (short)(u1 >> 16);
  const float r2 = r1 - __builtin_bit_cast(float, u1 & 0xffff0000u);
  l2 = (short)(__builtin_bit_cast(unsigned, r2) >> 16);
}

__device__ __forceinline__ void g2l16(const void* g, void* l) {
  __builtin_amdgcn_global_load_lds(
      (const __attribute__((address_space(1))) unsigned*)g,
      (__attribute__((address_space(3))) unsigned*)l, 16, 0, 0);
}

// Kernel 0: pack W into MFMA-B-fragment order, 3-term bf16 split.
// w*[s][nt][lane][j] = term of W[s*32 + (lane>>4)*8 + j][nt*16 + (lane&15)]
__global__ __launch_bounds__(256)
void moe_wpack(const float* __restrict__ wg, short* __restrict__ wh,
               short* __restrict__ wl, short* __restrict__ wl2) {
  const int tid = blockIdx.x * 256 + threadIdx.x;  // 0..16383 = (s, nt, lane)
  const int l  = tid & 63;
  const int nt = (tid >> 6) & 3;
  const int s  = tid >> 8;
  short8 a, b, c;
#pragma unroll
  for (int j = 0; j < 8; ++j) {
    const int k = s * 32 + (l >> 4) * 8 + j;
    const int n = nt * 16 + (l & 15);
    short xh, xl, xl2;
    split3(wg[(size_t)k * NEXP + n], xh, xl, xl2);
    a[j] = xh; b[j] = xl; c[j] = xl2;
  }
  *(short8*)(wh  + (size_t)tid * 8) = a;
  *(short8*)(wl  + (size_t)tid * 8) = b;
  *(short8*)(wl2 + (size_t)tid * 8) = c;
}

// Kernel 1: split-K MFMA partial GEMM (6-term bf16 split). Grid (256, ns) ->
// 4 blocks/CU = 16 waves/CU: the TLP that rounds 4-6 lacked. Per iteration:
// [12 w-frag loads] -> [stage x(c+1), 2 DMA] -> s_waitcnt vmcnt(14) (in-order:
// retires only the 2 oldest = DMA(c)) -> RAW s_barrier (no vmcnt(0) drain) ->
// compute. Triple-buffered xs covers the stage-before-barrier window.
__global__ __launch_bounds__(256, 4)
void moe_mfma_ks(const float* __restrict__ x, const short* __restrict__ wh,
                 const short* __restrict__ wl, const short* __restrict__ wl2,
                 float* __restrict__ part, int Kc) {
  __shared__ float xs[3 * XSB];   // 24 KB, triple-buffered

  const int t    = threadIdx.x;
  const int lane = t & 63;
  const int wid  = t >> 6;
  const int row0 = blockIdx.x * BM;
  const int k0   = blockIdx.y * Kc;
  const int nch  = Kc >> 5;
  const int s0   = k0 >> 5;       // first global K-step index

  auto stage = [&](int b, int c) {
    // 512 granules (16B): G = (tok, slot); src granule = slot ^ (tok&7)
#pragma unroll
    for (int j = 0; j < 2; ++j) {
      const int G = j * 256 + t;
      const int tok = G >> 3, slot = G & 7;
      g2l16(x + (size_t)(row0 + tok) * KDIM + k0 + c * 32 + ((slot ^ (tok & 7)) << 2),
            xs + (size_t)b * XSB + (size_t)G * 4);
    }
  };

  f32x4 accB[4] = {};   // hh term (magnitude ~1)
  f32x4 accS[4] = {};   // correction terms (magnitude ~2^-8)
  const int trow = wid * 16 + (lane & 15);   // my A-row (local token)
  const int kb   = lane >> 4;                // my k-group of 8
  const int sw   = trow & 7;

  const short8* __restrict__ whv  = (const short8*)wh;
  const short8* __restrict__ wlv  = (const short8*)wl;
  const short8* __restrict__ wl2v = (const short8*)wl2;

  stage(0, 0);

  int bc = 0;                                // buffer holding chunk c
  for (int c = 0; c < nch; ++c) {
    // 1) w fragments for step s0+c — issued BEFORE the next stage
    short8 bh[4], bl[4], bl2[4];
#pragma unroll
    for (int nt = 0; nt < 4; ++nt) {
      const int fi = (s0 + c) * 256 + nt * 64 + lane;
      bh[nt]  = whv[fi];
      bl[nt]  = wlv[fi];
      bl2[nt] = wl2v[fi];
    }
    __builtin_amdgcn_sched_barrier(0);

    // 2) stage chunk c+1, then retire only DMA(c) (oldest 2 in the queue)
    const int bn = (bc == 2) ? 0 : bc + 1;
    if (c + 1 < nch) {
      stage(bn, c + 1);
      __builtin_amdgcn_sched_barrier(0);
      asm volatile("s_waitcnt vmcnt(14)" ::: "memory");  // 12 w + 2 new DMA remain
    } else {
      asm volatile("s_waitcnt vmcnt(12)" ::: "memory");  // 12 w remain
    }
    __builtin_amdgcn_sched_barrier(0);
    __builtin_amdgcn_s_barrier();       // RAW barrier: no vmcnt(0) drain
    __builtin_amdgcn_sched_barrier(0);

    // 3) compute step c from buf bc
    const float* xrow = xs + (size_t)bc * XSB + trow * 32;
    const float4 xa = *(const float4*)(xrow + (((kb * 2)     ^ sw) << 2));
    const float4 xb = *(const float4*)(xrow + (((kb * 2 + 1) ^ sw) << 2));
    short8 ah, al, al2;
#pragma unroll
    for (int e = 0; e < 4; ++e) {
      short h0, l0, m0, h1, l1, m1;
      split3(((const float*)&xa)[e], h0, l0, m0);
      split3(((const float*)&xb)[e], h1, l1, m1);
      ah[e] = h0; al[e] = l0; al2[e] = m0;
      ah[e + 4] = h1; al[e + 4] = l1; al2[e + 4] = m1;
    }
#pragma unroll
    for (int nt = 0; nt < 4; ++nt) {
      accB[nt] = __builtin_amdgcn_mfma_f32_16x16x32_bf16(ah,  bh[nt],  accB[nt], 0, 0, 0);
      accS[nt] = __builtin_amdgcn_mfma_f32_16x16x32_bf16(al,  bh[nt],  accS[nt], 0, 0, 0);
      accS[nt] = __builtin_amdgcn_mfma_f32_16x16x32_bf16(ah,  bl[nt],  accS[nt], 0, 0, 0);
      accS[nt] = __builtin_amdgcn_mfma_f32_16x16x32_bf16(al,  bl[nt],  accS[nt], 0, 0, 0);
      accS[nt] = __builtin_amdgcn_mfma_f32_16x16x32_bf16(ah,  bl2[nt], accS[nt], 0, 0, 0);
      accS[nt] = __builtin_amdgcn_mfma_f32_16x16x32_bf16(al2, bh[nt],  accS[nt], 0, 0, 0);
    }
    bc = bn;
  }

  // ---- write f32 partials. D: col=lane&15 (expert in nt), row=(lane>>4)*4+reg.
  const int sub = lane & 15;
  const int grp = lane >> 4;
  float* pp = part + ((size_t)blockIdx.y * TOKENS + row0 + wid * 16 + grp * 4) * NEXP + sub;
#pragma unroll
  for (int r = 0; r < 4; ++r)
#pragma unroll
    for (int nt = 0; nt < 4; ++nt)
      pp[(size_t)r * NEXP + nt * 16] = accB[nt][r] + accS[nt][r];
}

// Kernel 2: 16 lanes per token, 4 experts/lane (float4 loads).
// Butterfly reductions within 16-lane groups; 6 argmax rounds with jax
// tie-break (equal score -> lower index). out: indices then scores.
__global__ __launch_bounds__(256)
void moe_softmax_topk(const float* __restrict__ part, float* __restrict__ out, int ns) {
  const int lane = threadIdx.x & 63;
  const int wid  = threadIdx.x >> 6;
  const int sub  = lane & 15;
  const int tok  = blockIdx.x * 16 + wid * 4 + (lane >> 4);

  float v[4] = {0.f, 0.f, 0.f, 0.f};
  for (int ks = 0; ks < ns; ++ks) {
    const float4 p = *(const float4*)(part + ((size_t)ks * TOKENS + tok) * NEXP + sub * 4);
    v[0] += p.x; v[1] += p.y; v[2] += p.z; v[3] += p.w;
  }

  float m = fmaxf(fmaxf(v[0], v[1]), fmaxf(v[2], v[3]));
#pragma unroll
  for (int off = 1; off < 16; off <<= 1) m = fmaxf(m, __shfl_xor(m, off));
  float p0 = expf(v[0] - m), p1 = expf(v[1] - m), p2 = expf(v[2] - m), p3 = expf(v[3] - m);
  float s = p0 + p1 + p2 + p3;
#pragma unroll
  for (int off = 1; off < 16; off <<= 1) s += __shfl_xor(s, off);
  v[0] = p0 / s; v[1] = p1 / s; v[2] = p2 / s; v[3] = p3 / s;

  float resv = 0.f; int resi = 0;
#pragma unroll
  for (int rr = 0; rr < TOPK; ++rr) {
    float bv = v[0]; int bi = sub * 4;
#pragma unroll
    for (int j = 1; j < 4; ++j)
      if (v[j] > bv) { bv = v[j]; bi = sub * 4 + j; }   // strict > : lowest idx on tie
#pragma unroll
    for (int off = 1; off < 16; off <<= 1) {
      const float ov = __shfl_xor(bv, off);
      const int   oi = __shfl_xor(bi, off);
      if (ov > bv || (ov == bv && oi < bi)) { bv = ov; bi = oi; }
    }
    if (sub == rr) { resv = bv; resi = bi; }
    if ((bi >> 2) == sub) v[bi & 3] = -1.f;   // scores > 0, sentinel safe
  }

  if (sub < TOPK) {
    out[(size_t)tok * TOPK + sub] = (float)resi;
    out[(size_t)TOKENS * TOPK + (size_t)tok * TOPK + sub] = resv;
  }
}

extern "C" void kernel_launch(void* const* d_in, const int* in_sizes, int n_in,
                              void* d_out, int out_size, void* d_ws, size_t ws_size,
                              hipStream_t stream) {
  const float* x  = (const float*)d_in[0];
  const float* wg = (const float*)d_in[1];
  float* out = (float*)d_out;

  short* wh  = (short*)d_ws;                        // 3 x 131072 shorts = 768 KB
  short* wl  = wh + (size_t)NSTEPS * 4 * 64 * 8;
  short* wl2 = wl + (size_t)NSTEPS * 4 * 64 * 8;
  const size_t wbytes = (size_t)3 * NSTEPS * 4 * 64 * 8 * sizeof(short);
  float* part = (float*)((char*)d_ws + wbytes);

  int ns = 4;
  while (ns > 1 && wbytes + (size_t)ns * TOKENS * NEXP * sizeof(float) > ws_size) ns >>= 1;
  const int Kc = KDIM / ns;

  moe_wpack<<<dim3(64), dim3(256), 0, stream>>>(wg, wh, wl, wl2);
  moe_mfma_ks<<<dim3(TOKENS / BM, ns), dim3(256), 0, stream>>>(x, wh, wl, wl2, part, Kc);
  moe_softmax_topk<<<dim3(TOKENS / 16), dim3(256), 0, stream>>>(part, out, ns);
}